// Round 3
// baseline (193.148 us; speedup 1.0000x reference)
//
#include <hip/hip_runtime.h>
#include <math.h>

// SANet attention, MFMA flash + split-K. b=4, c=64, HW=4096, fp32 in/out.
// out[b,0:64,:] = content ; out[b,64:128,q] = sum_k Fst[:,k] softmax_k(Fc[:,q].Fs[:,k])
//
// prep_k: content copy + Vt[b][c][k]=(f16)Fst (natural) + Kt[b][k][c]=(f16)Fs (transposed).
// attn_k: 1 wave per (split, 16 q-rows); 16 K-tiles per split; online softmax;
//         writes unnormalized partial O^T + (m,l) to ws.  Grid 4096 waves = 4 waves/SIMD.
// combine_k: merges 4 splits per output element.
//
// mfma_f32_16x16x32_f16: A[m=lane&15][k=quad*8+j], B[k=quad*8+j][n=lane&15],
// D[m=quad*4+reg][n=lane&15]  (quad = lane>>4).
// S-mfma computes S^T tile (m=k_key, n=q); PV computes O^T (m=c, n=q).

#define Bb 4
#define Cc 64
#define HWs 4096
#define SPLITS 4
#define TILES_PER_SPLIT 16   // 64 K-tiles / 4 splits

typedef _Float16 half8 __attribute__((ext_vector_type(8)));
typedef _Float16 half4 __attribute__((ext_vector_type(4)));
typedef float floatx4 __attribute__((ext_vector_type(4)));

__global__ __launch_bounds__(256) void prep_k(const float* __restrict__ content,
                                              const float* __restrict__ Fs,
                                              const float* __restrict__ Fst,
                                              float* __restrict__ out,
                                              _Float16* __restrict__ Kt,
                                              _Float16* __restrict__ Vt) {
    const int bid = blockIdx.x;
    const int t = threadIdx.x;
    if (bid < 1024) {
        // content copy (float4) + V f16 convert (same linear layout)
        int i4 = bid * 256 + t;                       // 0..262143
        const float4* c4 = (const float4*)content;
        const float4* v4 = (const float4*)Fst;
        float4* o4 = (float4*)out;
        int b = i4 >> 16, rem = i4 & 65535;
        o4[(size_t)b * 131072 + rem] = c4[i4];        // out batch stride 2*64*4096 f32
        float4 v = v4[i4];
        half4 h;
        h[0] = (_Float16)v.x; h[1] = (_Float16)v.y;
        h[2] = (_Float16)v.z; h[3] = (_Float16)v.w;
        *(half4*)(Vt + (size_t)i4 * 4) = h;
    } else {
        // transpose+convert one 64c x 64hw tile of Fs -> Kt
        __shared__ _Float16 T[64][80];                // hw x c, padded
        int e = bid - 1024;                           // 0..255
        int b = e >> 6;
        int hw0 = (e & 63) * 64;
        const float* sb = Fs + (size_t)b * Cc * HWs;
        #pragma unroll
        for (int r = 0; r < 4; ++r) {
            int idx = r * 256 + t;                    // 0..1023
            int c = idx >> 4, x4 = (idx & 15) * 4;
            float4 v = *(const float4*)(sb + (size_t)c * HWs + hw0 + x4);
            T[x4 + 0][c] = (_Float16)v.x;
            T[x4 + 1][c] = (_Float16)v.y;
            T[x4 + 2][c] = (_Float16)v.z;
            T[x4 + 3][c] = (_Float16)v.w;
        }
        __syncthreads();
        _Float16* db = Kt + (size_t)b * HWs * Cc;
        #pragma unroll
        for (int r = 0; r < 2; ++r) {
            int idx = r * 256 + t;                    // 0..511
            int row = idx >> 3, g = idx & 7;
            *(half8*)(db + (size_t)(hw0 + row) * Cc + g * 8) = *(half8*)&T[row][g * 8];
        }
    }
}

__global__ __launch_bounds__(64, 4) void attn_k(const float* __restrict__ Fc,
                                                const _Float16* __restrict__ Kt,
                                                const _Float16* __restrict__ Vt,
                                                float* __restrict__ Opart,
                                                float2* __restrict__ ml) {
    const int lane = threadIdx.x;
    const int quad = lane >> 4;
    const int l15  = lane & 15;
    // block id: [split][b][qtile]  (qtile fastest)
    const int qt_i = blockIdx.x & 255;
    const int b    = (blockIdx.x >> 8) & 3;
    const int s    = blockIdx.x >> 10;
    const int q0   = qt_i * 16;

    __shared__ _Float16 Ps[16][80];   // P^T round-trip buffer, q x k, padded (per-wave)

    const float*    Fcb = Fc + (size_t)b * Cc * HWs;
    const _Float16* Kb  = Kt + (size_t)b * HWs * Cc;
    const _Float16* Vb  = Vt + (size_t)b * Cc * HWs;

    // Q B-frags from fp32 Fc (one-time, 16 strided scalar loads):
    // B[k=c][n=q]: qf0[j] = Fc[c=quad*8+j][q0+l15], qf1 -> c+32
    half8 qf0, qf1;
    #pragma unroll
    for (int j = 0; j < 8; ++j) {
        qf0[j] = (_Float16)Fcb[(size_t)(quad * 8 + j) * HWs + q0 + l15];
        qf1[j] = (_Float16)Fcb[(size_t)(32 + quad * 8 + j) * HWs + q0 + l15];
    }

    floatx4 acc[4];
    #pragma unroll
    for (int m = 0; m < 4; ++m) acc[m] = (floatx4)(0.0f);
    float m_run = -INFINITY, l_run = 0.0f;

    const int kt0 = s * TILES_PER_SPLIT;
    for (int kt = kt0; kt < kt0 + TILES_PER_SPLIT; ++kt) {
        const int k0 = kt * 64;
        // K A-frags: A[m=k_local][k=c], k_local = m*16+l15, c = cs*32+quad*8+j
        half8 ka[4][2];
        #pragma unroll
        for (int m = 0; m < 4; ++m)
            #pragma unroll
            for (int cs = 0; cs < 2; ++cs)
                ka[m][cs] = *(const half8*)(Kb + (size_t)(k0 + m * 16 + l15) * Cc + cs * 32 + quad * 8);
        // V A-frags: A[c=m*16+l15][k=ks*32+quad*8+j]
        half8 va[4][2];
        #pragma unroll
        for (int m = 0; m < 4; ++m)
            #pragma unroll
            for (int ks = 0; ks < 2; ++ks)
                va[m][ks] = *(const half8*)(Vb + (size_t)(m * 16 + l15) * HWs + k0 + ks * 32 + quad * 8);

        // S^T tile: D[m=k_local][n=q]
        floatx4 sv[4];
        #pragma unroll
        for (int m = 0; m < 4; ++m) {
            sv[m] = __builtin_amdgcn_mfma_f32_16x16x32_f16(ka[m][0], qf0, (floatx4)(0.0f), 0, 0, 0);
            sv[m] = __builtin_amdgcn_mfma_f32_16x16x32_f16(ka[m][1], qf1, sv[m], 0, 0, 0);
        }

        // online softmax over k (in-lane 16 values + shfl across quads)
        float mx = -INFINITY;
        #pragma unroll
        for (int m = 0; m < 4; ++m)
            #pragma unroll
            for (int r = 0; r < 4; ++r) mx = fmaxf(mx, sv[m][r]);
        mx = fmaxf(mx, __shfl_xor(mx, 16));
        mx = fmaxf(mx, __shfl_xor(mx, 32));
        float m_new = fmaxf(m_run, mx);
        float alpha = __expf(m_run - m_new);          // 0 on first tile
        float ps = 0.0f;
        #pragma unroll
        for (int m = 0; m < 4; ++m)
            #pragma unroll
            for (int r = 0; r < 4; ++r) {
                float e = __expf(sv[m][r] - m_new);
                sv[m][r] = e;
                ps += e;
            }
        ps += __shfl_xor(ps, 16);
        ps += __shfl_xor(ps, 32);
        l_run = l_run * alpha + ps;
        m_run = m_new;
        #pragma unroll
        for (int m = 0; m < 4; ++m)
            #pragma unroll
            for (int r = 0; r < 4; ++r) acc[m][r] *= alpha;

        // P^T C-layout -> LDS Ps[q][k] (wave-private, no barrier)
        #pragma unroll
        for (int m = 0; m < 4; ++m) {
            half4 p;
            p[0] = (_Float16)sv[m][0]; p[1] = (_Float16)sv[m][1];
            p[2] = (_Float16)sv[m][2]; p[3] = (_Float16)sv[m][3];
            *(half4*)&Ps[l15][m * 16 + quad * 4] = p;
        }
        half8 pb0 = *(half8*)&Ps[l15][quad * 8];
        half8 pb1 = *(half8*)&Ps[l15][32 + quad * 8];

        // O^T update: D[m=c][n=q]
        #pragma unroll
        for (int m = 0; m < 4; ++m) {
            acc[m] = __builtin_amdgcn_mfma_f32_16x16x32_f16(va[m][0], pb0, acc[m], 0, 0, 0);
            acc[m] = __builtin_amdgcn_mfma_f32_16x16x32_f16(va[m][1], pb1, acc[m], 0, 0, 0);
        }
    }

    // write unnormalized partial O^T and (m,l)
    float* op = Opart + (((size_t)s * Bb + b) * Cc) * HWs;
    #pragma unroll
    for (int m = 0; m < 4; ++m)
        #pragma unroll
        for (int r = 0; r < 4; ++r) {
            int c = m * 16 + quad * 4 + r;
            op[(size_t)c * HWs + q0 + l15] = acc[m][r];
        }
    if (quad == 0)
        ml[((size_t)b * HWs + q0 + l15) * SPLITS + s] = make_float2(m_run, l_run);
}

__global__ __launch_bounds__(256) void combine_k(const float* __restrict__ Opart,
                                                 const float2* __restrict__ ml,
                                                 float* __restrict__ out) {
    int idx = blockIdx.x * 256 + threadIdx.x;         // over 4*64*4096 = 1M
    int q = idx & 4095;
    int c = (idx >> 12) & 63;
    int b = idx >> 18;
    const float2* mlp = ml + ((size_t)b * HWs + q) * SPLITS;
    float2 mls[SPLITS];
    #pragma unroll
    for (int s = 0; s < SPLITS; ++s) mls[s] = mlp[s];
    float M = -INFINITY;
    #pragma unroll
    for (int s = 0; s < SPLITS; ++s) M = fmaxf(M, mls[s].x);
    float l = 0.0f, w[SPLITS];
    #pragma unroll
    for (int s = 0; s < SPLITS; ++s) {
        w[s] = __expf(mls[s].x - M);
        l += w[s] * mls[s].y;
    }
    float o = 0.0f;
    #pragma unroll
    for (int s = 0; s < SPLITS; ++s)
        o += w[s] * Opart[(((size_t)s * Bb + b) * Cc + c) * HWs + q];
    out[((size_t)b * 2 * Cc + Cc + c) * HWs + q] = o / l;
}

extern "C" void kernel_launch(void* const* d_in, const int* in_sizes, int n_in,
                              void* d_out, int out_size, void* d_ws, size_t ws_size,
                              hipStream_t stream) {
    const float* content   = (const float*)d_in[0];
    const float* content_s = (const float*)d_in[1];
    const float* style     = (const float*)d_in[2];
    float* out = (float*)d_out;

    _Float16* Kt = (_Float16*)d_ws;                           // [4][4096][64] f16  (2 MB)
    _Float16* Vt = Kt + (size_t)Bb * HWs * Cc;                // [4][64][4096] f16  (2 MB)
    float*    Opart = (float*)(Vt + (size_t)Bb * Cc * HWs);   // [4][4][64][4096]  (16.8 MB)
    float2*   ml = (float2*)(Opart + (size_t)SPLITS * Bb * Cc * HWs);  // [4][4096][4] (512 KB)

    prep_k<<<dim3(1280), dim3(256), 0, stream>>>(content, content_s, style, out, Kt, Vt);
    attn_k<<<dim3(SPLITS * Bb * (HWs / 16)), dim3(64), 0, stream>>>(content, Kt, Vt, Opart, ml);
    combine_k<<<dim3(4096), dim3(256), 0, stream>>>(Opart, ml, out);
}